// Round 4
// baseline (603.321 us; speedup 1.0000x reference)
//
#include <hip/hip_runtime.h>

// GroupedEmbeddingBag: T=8 tables [V=100000, D=128] fp32, B=4096 bags/table.
// out[b, t*D+d] = sum_{i in [offs[t][b], offs[t][b+1])} tables[t][values[t][i]][d] * psw[t][i]
//
// R3: scalar-index + sustained-MLP gather loop (one wave per bag, one 512B row
//     per wave-load with SGPR base, 16 rows in flight). Measured 565.8 us —
//     flat vs R1 (573.9). Latency theory dead.
// R5: random->sequential HBM conversion. Both prior kernels pin at 1.5 TB/s
//     logical = ~1/4 of streaming DRAM rate, the classic random-row-activate
//     penalty: the harness's 1.6 GB poison fill flushes L3 every iteration,
//     so every first-touch 512B gather is a random HBM access.
//     Fix: each block sequentially prestreams its private 50 KB slice of its
//     table at kernel start (1024 blocks/table x 50 KB = exactly the 51.2 MB
//     table, zero duplication). Streaming warms L3 at full DRAM efficiency;
//     the unchanged gather loop then hits L3 instead of random-cold HBM.
//     Predict 565 -> ~250-350 us if the random-efficiency theory is right;
//     flat if dur_us is dominated by harness reset floor / L3-random ceiling.

namespace {
constexpr int T = 8;
constexpr int V = 100000;
constexpr int D = 128;
constexpr int B = 4096;
constexpr int N = 204800;
constexpr int BLOCKS_PER_TABLE = B / 4;                       // 1024
constexpr int F4_PER_TABLE = V * D / 4;                       // 3,200,000
constexpr int F4_PER_BLOCK = F4_PER_TABLE / BLOCKS_PER_TABLE; // 3125
}

__device__ __forceinline__ float readlane_f(float v, int l) {
    return __int_as_float(__builtin_amdgcn_readlane(__float_as_int(v), l));
}

__global__ __launch_bounds__(256) void grouped_ebag_kernel(
    const float* __restrict__ tables,   // [T, V, D]
    const int* __restrict__ values,     // [T, N]
    const int* __restrict__ offsets,    // [T, B+1]
    const float* __restrict__ psw,      // [T, N]
    float* __restrict__ out)            // [B, T*D]
{
    const int wave = threadIdx.x >> 6;            // 0..3
    const int lane = threadIdx.x & 63;
    const int bag  = (blockIdx.x << 2) + wave;    // (t, b) ordered
    const int t = bag >> 12;                      // B = 4096
    const int b = bag & (B - 1);

    const float* __restrict__ tab = tables + (size_t)t * (V * D);

    // ---- Phase 0: cooperative sequential prestream of this table into L2/L3.
    // Each block owns a disjoint 50 KB slice (3125 float4); 1024 blocks cover
    // the whole 51.2 MB table exactly once, as pure streaming DRAM traffic.
    {
        const float4* __restrict__ slice =
            (const float4*)tab +
            (size_t)(blockIdx.x & (BLOCKS_PER_TABLE - 1)) * F4_PER_BLOCK;
        float keep = 0.f;
#pragma unroll
        for (int k = 0; k < 13; ++k) {
            const int idx = k * 256 + (int)threadIdx.x;
            if (idx < F4_PER_BLOCK) {
                const float4 v4 = slice[idx];
                keep += v4.x + v4.y + v4.z + v4.w;   // forces the loads
            }
        }
        asm volatile("" :: "v"(keep));               // keep-alive, no DCE
    }

    int start = offsets[t * (B + 1) + b];
    int end   = offsets[t * (B + 1) + b + 1];
    start = __builtin_amdgcn_readfirstlane(start);
    end   = __builtin_amdgcn_readfirstlane(end);
    const int len = end - start;

    const int*   __restrict__ vals = values + (size_t)t * N + start;
    const float* __restrict__ wgt  = psw    + (size_t)t * N + start;

    float2 acc = make_float2(0.f, 0.f);

    for (int base = 0; base < len; base += 64) {
        const int rem = len - base;
        const int m   = rem < 64 ? rem : 64;      // rows in this chunk (1..64)

        // One coalesced vector load of up to 64 indices + 64 weights.
        const int pos  = base + lane;
        const int posc = pos < len ? pos : (len - 1);   // clamp: stay in-bag
        const int   vidx = vals[posc];
        const float vw   = (pos < len) ? wgt[posc] : 0.f;  // pad rows weigh 0

        const int ngrp = (m + 7) >> 3;            // 8-row groups, <= 8

        float2 bufA[8], bufB[8];                  // static-indexed only

        auto LOAD = [&](float2 (&buf)[8], int g) {
#pragma unroll
            for (int j = 0; j < 8; ++j) {
                const int r   = (g << 3) + j;                    // uniform
                const int row = __builtin_amdgcn_readlane(vidx, r); // SGPR idx
                buf[j] = *(const float2*)(tab + (size_t)row * D + lane * 2);
            }
        };
        auto FMA = [&](float2 (&buf)[8], int g) {
#pragma unroll
            for (int j = 0; j < 8; ++j) {
                const int r = (g << 3) + j;
                const float w = readlane_f(vw, r);               // SGPR weight
                acc.x = fmaf(buf[j].x, w, acc.x);
                acc.y = fmaf(buf[j].y, w, acc.y);
            }
        };

        LOAD(bufA, 0);
        int g = 0;
        for (; g + 2 <= ngrp; g += 2) {
            LOAD(bufB, g + 1);      // issue next 8 rows BEFORE waiting on A
            FMA(bufA, g);           // vmcnt(8): only A's rows drained
            if (g + 2 < ngrp) LOAD(bufA, g + 2);
            FMA(bufB, g + 1);
        }
        if (g < ngrp) FMA(bufA, g); // odd tail group
    }

    // Full row per wave: 512B contiguous store, no cross-lane reduce needed.
    *(float2*)(out + (size_t)b * (T * D) + t * D + lane * 2) = acc;
}

extern "C" void kernel_launch(void* const* d_in, const int* in_sizes, int n_in,
                              void* d_out, int out_size, void* d_ws, size_t ws_size,
                              hipStream_t stream) {
    const float* tables  = (const float*)d_in[0];
    const int*   values  = (const int*)d_in[1];
    const int*   offsets = (const int*)d_in[2];
    const float* psw     = (const float*)d_in[3];
    float*       out     = (float*)d_out;

    dim3 grid((T * B) / 4);   // 4 bags (waves) per 256-thread block
    dim3 block(256);
    grouped_ebag_kernel<<<grid, block, 0, stream>>>(tables, values, offsets, psw, out);
}